// Round 1
// baseline (198.793 us; speedup 1.0000x reference)
//
#include <hip/hip_runtime.h>
#include <stdint.h>

#define D_MODEL 1024
#define NHEAD   16
#define DK      64
#define BATCH   2
#define SEQ     2048
#define MTOT    (BATCH*SEQ)   // 4096

typedef unsigned short u16;
typedef u16    u16x4  __attribute__((ext_vector_type(4)));
typedef u16    u16x8  __attribute__((ext_vector_type(8)));
typedef __bf16 bf16x8 __attribute__((ext_vector_type(8)));
typedef float  f32x4  __attribute__((ext_vector_type(4)));

__device__ __forceinline__ u16 f2bf(float f) {
  union { float f; unsigned u; } v; v.f = f;
  return (u16)((v.u + 0x7fffu + ((v.u >> 16) & 1u)) >> 16);
}

__device__ __forceinline__ void gl_lds16(const void* g, void* l) {
  __builtin_amdgcn_global_load_lds((const __attribute__((address_space(1))) void*)g,
                                   (__attribute__((address_space(3))) void*)l, 16, 0, 0);
}

__device__ __forceinline__ bf16x8 ld_frag(const u16* p) {
  return __builtin_bit_cast(bf16x8, *(const u16x8*)p);
}

// ---------------- prep: x -> bf16 ----------------
__global__ __launch_bounds__(256) void k_cvt_x(const float* __restrict__ x, u16* __restrict__ xb) {
  int i = blockIdx.x * 256 + threadIdx.x;
  const float4 v = ((const float4*)x)[i];
  u16x4 o; o[0]=f2bf(v.x); o[1]=f2bf(v.y); o[2]=f2bf(v.z); o[3]=f2bf(v.w);
  *(u16x4*)(xb + (size_t)i*4) = o;
}

// ---------------- prep: W -> W^T bf16 ----------------
__global__ __launch_bounds__(256) void k_wtrans(const float* __restrict__ wq, const float* __restrict__ wk,
                                                const float* __restrict__ wv, const float* __restrict__ wo,
                                                u16* __restrict__ wqkv_t, u16* __restrict__ wo_t) {
  __shared__ float tile[32][33];
  const int z = blockIdx.z;
  const float* src = (z==0)?wq:(z==1)?wk:(z==2)?wv:wo;
  const int kb = blockIdx.y*32, nb = blockIdx.x*32;
  const int tx = threadIdx.x & 31, ty = threadIdx.x >> 5;  // 32 x 8
  #pragma unroll
  for (int i=0;i<4;i++)
    tile[ty + i*8][tx] = src[(size_t)(kb + ty + i*8)*D_MODEL + nb + tx];
  __syncthreads();
  u16* dst = (z<3) ? (wqkv_t + (size_t)z*D_MODEL*D_MODEL) : wo_t;
  #pragma unroll
  for (int i=0;i<4;i++) {
    int n = nb + ty + i*8, k = kb + tx;
    dst[(size_t)n*D_MODEL + k] = f2bf(tile[tx][ty + i*8]);
  }
}

// ---------------- prep: pack mask to bits ----------------
__global__ __launch_bounds__(256) void k_maskpack(const int* __restrict__ mask,
                                                  unsigned long long* __restrict__ mb) {
  const int wid = blockIdx.x*4 + (threadIdx.x >> 6);   // 0..4095
  const int lane = threadIdx.x & 63;
  for (int t2 = 0; t2 < 32; ++t2) {
    int word = wid*32 + t2;                 // 0..131071
    int row = word >> 5;                    // b*SEQ + i
    int kb = word & 31;
    int m = mask[(size_t)row*SEQ + kb*64 + lane];
    unsigned long long bits = __ballot(m != 0);
    if (lane == 0) mb[word] = bits;
  }
}

// ---------------- prep: V [bh][L][64] -> Vt [bh][64][L] ----------------
__global__ __launch_bounds__(256) void k_vtrans(const u16* __restrict__ V, u16* __restrict__ Vt) {
  __shared__ u16 tile[64][72];
  const int bh = blockIdx.x >> 5;
  const int l0 = (blockIdx.x & 31) * 64;
  const int t = threadIdx.x;
  const u16* src = V + ((size_t)bh*SEQ + l0)*DK;
  #pragma unroll
  for (int j=0;j<2;j++) {
    int idx = t + j*256;                 // 0..511
    int r = idx >> 3, c8 = (idx & 7)*8;
    *(u16x8*)&tile[r][c8] = *(const u16x8*)(src + (size_t)r*DK + c8);
  }
  __syncthreads();
  u16* dst = Vt + (size_t)bh*DK*SEQ + l0;
  #pragma unroll
  for (int j=0;j<2;j++) {
    int idx = t + j*256;
    int d = idx >> 3, k8 = (idx & 7)*8;
    u16x8 o;
    #pragma unroll
    for (int e=0;e<8;e++) o[e] = tile[k8 + e][d];
    *(u16x8*)(dst + (size_t)d*SEQ + k8) = o;
  }
}

// ---------------- 128x128 MFMA GEMM, C = A @ Bt^T (+epilogue) ----------------
// A: [M][K] bf16 row-major;  Bt: [N][K] bf16 (i.e., B transposed)
// EPI 0: QKV epilogue (bias add, Q prescale, per-head scatter)
// EPI 1: out epilogue (bias add, f32 write)
template<int EPI>
__global__ __launch_bounds__(256) void k_gemm(const u16* __restrict__ A, const u16* __restrict__ Bt,
                                              const int M, const int N, const int K, const int nbm,
                                              const float* __restrict__ bq, const float* __restrict__ bk,
                                              const float* __restrict__ bv,
                                              u16* __restrict__ Qo, u16* __restrict__ Ko, u16* __restrict__ Vo,
                                              const float* __restrict__ bo, float* __restrict__ out) {
  __shared__ u16 As[128*32];
  __shared__ u16 Bs[128*32];
  const int t = threadIdx.x, lane = t & 63, w = t >> 6;
  const int bm = blockIdx.x % nbm, bn = blockIdx.x / nbm;
  const int brow = bm*128, bcol = bn*128;

  // staging: 8 chunks of 1024B per tile; wave w owns chunks 2w, 2w+1.
  // LDS layout linear [row][4 slots of 16B]; logical slot stored at slot^(row&3)
  // (pre-swizzled global source, linear LDS write -> both-sides swizzle).
  const int srow = w*32 + (lane >> 2);                   // rows for chunk 2w
  const int sswz = (lane & 3) ^ ((lane >> 2) & 3);
  const u16* aS0 = A  + (size_t)(brow + srow)*K + sswz*8;
  const u16* aS1 = aS0 + (size_t)16*K;
  const u16* bS0 = Bt + (size_t)(bcol + srow)*K + sswz*8;
  const u16* bS1 = bS0 + (size_t)16*K;
  u16* aD0 = As + w*1024; u16* aD1 = aD0 + 512;
  u16* bD0 = Bs + w*1024; u16* bD1 = bD0 + 512;

  const int wr = w >> 1, wc = w & 1;
  const int slotA = (lane >> 4) ^ (lane & 3);            // reader swizzle
  const u16* aRd = As + (wr*64 + (lane & 15))*32 + slotA*8;
  const u16* bRd = Bs + (wc*64 + (lane & 15))*32 + slotA*8;

  f32x4 acc[4][4];
  #pragma unroll
  for (int i=0;i<4;i++)
    #pragma unroll
    for (int j=0;j<4;j++) acc[i][j] = (f32x4){0.f,0.f,0.f,0.f};

  for (int kt = 0; kt < K; kt += 32) {
    gl_lds16(aS0 + kt, aD0);
    gl_lds16(aS1 + kt, aD1);
    gl_lds16(bS0 + kt, bD0);
    gl_lds16(bS1 + kt, bD1);
    __syncthreads();
    bf16x8 af[4], bfr[4];
    #pragma unroll
    for (int m=0;m<4;m++) af[m] = ld_frag(aRd + m*512);
    #pragma unroll
    for (int n=0;n<4;n++) bfr[n] = ld_frag(bRd + n*512);
    #pragma unroll
    for (int m=0;m<4;m++)
      #pragma unroll
      for (int n=0;n<4;n++)
        acc[m][n] = __builtin_amdgcn_mfma_f32_16x16x32_bf16(af[m], bfr[n], acc[m][n], 0,0,0);
    __syncthreads();
  }

  const int orow = brow + wr*64 + (lane >> 4)*4;   // + m*16 + j
  const int ocol = bcol + wc*64 + (lane & 15);     // + n*16
  if (EPI == 0) {
    const int mat = ocol >> 10;                    // uniform per block (128 | 1024)
    const float* bias = (mat==0) ? bq : (mat==1) ? bk : bv;
    u16* outp = (mat==0) ? Qo : (mat==1) ? Ko : Vo;
    const float scal = (mat==0) ? 0.125f : 1.0f;   // 1/sqrt(64) folded into Q
    #pragma unroll
    for (int m=0;m<4;m++) {
      #pragma unroll
      for (int n=0;n<4;n++) {
        int col = ocol + n*16;
        int c = col & 1023;
        float bb = bias[c];
        int h = c >> 6, d = c & 63;
        #pragma unroll
        for (int j=0;j<4;j++) {
          int row = orow + m*16 + j;
          int b = row >> 11, l = row & 2047;
          float v = (acc[m][n][j] + bb) * scal;
          outp[(((size_t)(b*NHEAD + h)*SEQ + l) << 6) + d] = f2bf(v);
        }
      }
    }
  } else {
    #pragma unroll
    for (int m=0;m<4;m++)
      #pragma unroll
      for (int n=0;n<4;n++) {
        int col = ocol + n*16;
        float bb = bo[col];
        #pragma unroll
        for (int j=0;j<4;j++) {
          int row = orow + m*16 + j;
          out[(size_t)row*N + col] = acc[m][n][j] + bb;
        }
      }
  }
}

// ---------------- flash attention ----------------
// Block: 4 waves, 64 q-rows per block (16 per wave). K/V tiles of 64 keys in LDS.
// S^T = mfma(K, Q) so per-q softmax is lane-local in lane&15.
__global__ __launch_bounds__(256) void k_attn(const u16* __restrict__ Q, const u16* __restrict__ K,
                                              const u16* __restrict__ Vt,
                                              const unsigned long long* __restrict__ MB,
                                              u16* __restrict__ AO) {
  __shared__ u16 Ks[64*64];
  __shared__ u16 Vs[64*64];
  __shared__ u16 Pl[4][16*72];           // per-wave P tile, padded stride 72
  const int t = threadIdx.x, lane = t & 63, w = t >> 6;
  const int bh = blockIdx.x >> 5;
  const int q0 = (blockIdx.x & 31) * 64;
  const int b = bh >> 4, h = bh & 15;

  const int qrow = q0 + w*16 + (lane & 15);
  const u16* qp = Q + ((size_t)bh*SEQ + qrow)*DK + (lane >> 4)*8;
  const bf16x8 qf0 = ld_frag(qp);
  const bf16x8 qf1 = ld_frag(qp + 32);

  // staging: 8 chunks of 1024B (8 rows of 128B); wave w owns chunks 2w,2w+1.
  const int srow = w*16 + (lane >> 3);
  const int sswz = (lane & 7) ^ ((lane >> 3) & 7);
  const u16* kS0 = K  + ((size_t)bh*SEQ + srow)*DK + sswz*8;
  const u16* kS1 = kS0 + 8*DK;
  const u16* vS0 = Vt + ((size_t)bh*DK + srow)*SEQ + sswz*8;
  const u16* vS1 = vS0 + 8*SEQ;
  u16* kD0 = Ks + w*1024; u16* kD1 = kD0 + 512;
  u16* vD0 = Vs + w*1024; u16* vD1 = vD0 + 512;

  const int rowL = lane & 15;
  const int sl0 = (lane >> 4) ^ (lane & 7);
  const int sl1 = ((lane >> 4) + 4) ^ (lane & 7);

  f32x4 o[4];
  #pragma unroll
  for (int i=0;i<4;i++) o[i] = (f32x4){0.f,0.f,0.f,0.f};
  float m_run = -1e30f, l_run = 0.f;
  const float LOG2E = 1.4426950408889634f;
  const unsigned long long* mbp = MB + ((size_t)b*SEQ + qrow)*32;

  for (int kt = 0; kt < SEQ/64; ++kt) {
    gl_lds16(kS0, kD0); gl_lds16(kS1, kD1);
    gl_lds16(vS0, vD0); gl_lds16(vS1, vD1);
    kS0 += 64*DK; kS1 += 64*DK; vS0 += 64; vS1 += 64;
    __syncthreads();

    // S^T[key][q] for 64 keys
    f32x4 s[4];
    #pragma unroll
    for (int kn=0;kn<4;kn++) {
      const u16* kr = Ks + (kn*16 + rowL)*DK;
      bf16x8 k0 = ld_frag(kr + sl0*8);
      bf16x8 k1 = ld_frag(kr + sl1*8);
      f32x4 sv = (f32x4){0.f,0.f,0.f,0.f};
      sv = __builtin_amdgcn_mfma_f32_16x16x32_bf16(k0, qf0, sv, 0,0,0);
      sv = __builtin_amdgcn_mfma_f32_16x16x32_bf16(k1, qf1, sv, 0,0,0);
      s[kn] = sv;
    }

    unsigned long long mb = mbp[kt];
    if (mb != ~0ull) {
      #pragma unroll
      for (int kn=0;kn<4;kn++)
        #pragma unroll
        for (int j=0;j<4;j++) {
          int kl = kn*16 + (lane >> 4)*4 + j;
          if (!((mb >> kl) & 1ull)) s[kn][j] = -1e9f;
        }
    }

    // online softmax (per q = lane&15)
    float mx = -1e30f;
    #pragma unroll
    for (int kn=0;kn<4;kn++)
      #pragma unroll
      for (int j=0;j<4;j++) mx = fmaxf(mx, s[kn][j]);
    mx = fmaxf(mx, __shfl_xor(mx, 16));
    mx = fmaxf(mx, __shfl_xor(mx, 32));
    float m_new = fmaxf(m_run, mx);
    float corr = exp2f((m_run - m_new) * LOG2E);
    float ps = 0.f;
    #pragma unroll
    for (int kn=0;kn<4;kn++) {
      u16x4 pk;
      #pragma unroll
      for (int j=0;j<4;j++) {
        float p = exp2f((s[kn][j] - m_new) * LOG2E);
        ps += p;
        pk[j] = f2bf(p);
      }
      *(u16x4*)&Pl[w][rowL*72 + kn*16 + (lane >> 4)*4] = pk;
    }
    ps += __shfl_xor(ps, 16);
    ps += __shfl_xor(ps, 32);
    l_run = l_run * corr + ps;
    m_run = m_new;

    // rescale O (rows q = (lane>>4)*4+j)
    #pragma unroll
    for (int j=0;j<4;j++) {
      float cj = __shfl(corr, (lane >> 4)*4 + j);
      #pragma unroll
      for (int nd=0;nd<4;nd++) o[nd][j] *= cj;
    }

    // PV
    bf16x8 pa0 = ld_frag(&Pl[w][rowL*72 + (lane >> 4)*8]);
    bf16x8 pa1 = ld_frag(&Pl[w][rowL*72 + 32 + (lane >> 4)*8]);
    #pragma unroll
    for (int nd=0;nd<4;nd++) {
      const u16* vr = Vs + (nd*16 + rowL)*DK;
      bf16x8 v0 = ld_frag(vr + sl0*8);
      bf16x8 v1 = ld_frag(vr + sl1*8);
      o[nd] = __builtin_amdgcn_mfma_f32_16x16x32_bf16(pa0, v0, o[nd], 0,0,0);
      o[nd] = __builtin_amdgcn_mfma_f32_16x16x32_bf16(pa1, v1, o[nd], 0,0,0);
    }
    __syncthreads();
  }

  #pragma unroll
  for (int j=0;j<4;j++) {
    float lj = __shfl(l_run, (lane >> 4)*4 + j);
    float inv = 1.0f / lj;
    int qg = q0 + w*16 + (lane >> 4)*4 + j;
    size_t base = ((size_t)(b*SEQ + qg))*D_MODEL + h*DK;
    #pragma unroll
    for (int nd=0;nd<4;nd++)
      AO[base + nd*16 + (lane & 15)] = f2bf(o[nd][j] * inv);
  }
}

extern "C" void kernel_launch(void* const* d_in, const int* in_sizes, int n_in,
                              void* d_out, int out_size, void* d_ws, size_t ws_size,
                              hipStream_t stream) {
  const float* x  = (const float*)d_in[0];
  const int*  msk = (const int*)d_in[1];
  const float* wq = (const float*)d_in[2];
  const float* bq = (const float*)d_in[3];
  const float* wk = (const float*)d_in[4];
  const float* bk = (const float*)d_in[5];
  const float* wv = (const float*)d_in[6];
  const float* bv = (const float*)d_in[7];
  const float* wo = (const float*)d_in[8];
  const float* bo = (const float*)d_in[9];
  float* out = (float*)d_out;

  char* ws = (char*)d_ws;
  size_t off = 0;
  u16* Xb   = (u16*)(ws + off); off += (size_t)MTOT*D_MODEL*2;        // 8.4 MB
  u16* Wqkv = (u16*)(ws + off); off += (size_t)3*D_MODEL*D_MODEL*2;   // 6.3 MB
  u16* Wot  = (u16*)(ws + off); off += (size_t)D_MODEL*D_MODEL*2;     // 2.1 MB
  u16* Qb   = (u16*)(ws + off); off += (size_t)BATCH*NHEAD*SEQ*DK*2;  // 8.4 MB
  u16* Kb   = (u16*)(ws + off); off += (size_t)BATCH*NHEAD*SEQ*DK*2;
  u16* Vb   = (u16*)(ws + off); off += (size_t)BATCH*NHEAD*SEQ*DK*2;
  u16* Vtb  = (u16*)(ws + off); off += (size_t)BATCH*NHEAD*SEQ*DK*2;
  u16* AO   = (u16*)(ws + off); off += (size_t)MTOT*D_MODEL*2;
  unsigned long long* Mb = (unsigned long long*)(ws + off);           // 1 MB
  // total ~59.8 MB of d_ws

  k_cvt_x<<<MTOT*D_MODEL/4/256, 256, 0, stream>>>(x, Xb);
  k_wtrans<<<dim3(32,32,4), 256, 0, stream>>>(wq, wk, wv, wo, Wqkv, Wot);
  k_maskpack<<<1024, 256, 0, stream>>>(msk, Mb);
  k_gemm<0><<<(MTOT/128)*(3*D_MODEL/128), 256, 0, stream>>>(
      Xb, Wqkv, MTOT, 3*D_MODEL, D_MODEL, MTOT/128,
      bq, bk, bv, Qb, Kb, Vb, nullptr, nullptr);
  k_vtrans<<<BATCH*NHEAD*(SEQ/64), 256, 0, stream>>>(Vb, Vtb);
  k_attn<<<BATCH*NHEAD*(SEQ/64), 256, 0, stream>>>(Qb, Kb, Vtb, Mb, AO);
  k_gemm<1><<<(MTOT/128)*(D_MODEL/128), 256, 0, stream>>>(
      AO, Wot, MTOT, D_MODEL, D_MODEL, MTOT/128,
      nullptr, nullptr, nullptr, nullptr, nullptr, nullptr, bo, out);
}

// Round 2
// 154.115 us; speedup vs baseline: 1.2899x; 1.2899x over previous
//
#include <hip/hip_runtime.h>
#include <stdint.h>

#define D_MODEL 1024
#define NHEAD   16
#define DK      64
#define BATCH   2
#define SEQ     2048
#define MTOT    (BATCH*SEQ)   // 4096

typedef unsigned short u16;
typedef unsigned int   u32;
typedef u16    u16x4  __attribute__((ext_vector_type(4)));
typedef u16    u16x8  __attribute__((ext_vector_type(8)));
typedef u32    u32x4  __attribute__((ext_vector_type(4)));
typedef __bf16 bf16x8 __attribute__((ext_vector_type(8)));
typedef float  f32x4  __attribute__((ext_vector_type(4)));
typedef float  f32x16 __attribute__((ext_vector_type(16)));

__device__ __forceinline__ u16 f2bf(float f) {
  union { float f; unsigned u; } v; v.f = f;
  return (u16)((v.u + 0x7fffu + ((v.u >> 16) & 1u)) >> 16);
}

__device__ __forceinline__ void gl_lds16(const void* g, void* l) {
  __builtin_amdgcn_global_load_lds((const __attribute__((address_space(1))) void*)g,
                                   (__attribute__((address_space(3))) void*)l, 16, 0, 0);
}

__device__ __forceinline__ bf16x8 ld_frag(const u16* p) {
  return __builtin_bit_cast(bf16x8, *(const u16x8*)p);
}

__device__ __forceinline__ u32 cvtpk(float lo, float hi) {
  u32 r;
  asm("v_cvt_pk_bf16_f32 %0, %1, %2" : "=v"(r) : "v"(lo), "v"(hi));
  return r;
}

// ---------------- prep: x -> bf16 ----------------
__global__ __launch_bounds__(256) void k_cvt_x(const float* __restrict__ x, u16* __restrict__ xb) {
  int i = blockIdx.x * 256 + threadIdx.x;
  const float4 v = ((const float4*)x)[i];
  u16x4 o; o[0]=f2bf(v.x); o[1]=f2bf(v.y); o[2]=f2bf(v.z); o[3]=f2bf(v.w);
  *(u16x4*)(xb + (size_t)i*4) = o;
}

// ---------------- prep: W -> W^T bf16 ----------------
__global__ __launch_bounds__(256) void k_wtrans(const float* __restrict__ wq, const float* __restrict__ wk,
                                                const float* __restrict__ wv, const float* __restrict__ wo,
                                                u16* __restrict__ wqkv_t, u16* __restrict__ wo_t) {
  __shared__ float tile[32][33];
  const int z = blockIdx.z;
  const float* src = (z==0)?wq:(z==1)?wk:(z==2)?wv:wo;
  const int kb = blockIdx.y*32, nb = blockIdx.x*32;
  const int tx = threadIdx.x & 31, ty = threadIdx.x >> 5;  // 32 x 8
  #pragma unroll
  for (int i=0;i<4;i++)
    tile[ty + i*8][tx] = src[(size_t)(kb + ty + i*8)*D_MODEL + nb + tx];
  __syncthreads();
  u16* dst = (z<3) ? (wqkv_t + (size_t)z*D_MODEL*D_MODEL) : wo_t;
  #pragma unroll
  for (int i=0;i<4;i++) {
    int n = nb + ty + i*8, k = kb + tx;
    dst[(size_t)n*D_MODEL + k] = f2bf(tile[tx][ty + i*8]);
  }
}

// ---------------- prep: pack mask to bits ----------------
__global__ __launch_bounds__(256) void k_maskpack(const int* __restrict__ mask,
                                                  unsigned long long* __restrict__ mb) {
  const int wid = blockIdx.x*4 + (threadIdx.x >> 6);   // 0..4095
  const int lane = threadIdx.x & 63;
  for (int t2 = 0; t2 < 32; ++t2) {
    int word = wid*32 + t2;                 // 0..131071
    int row = word >> 5;                    // b*SEQ + i
    int kb = word & 31;
    int m = mask[(size_t)row*SEQ + kb*64 + lane];
    unsigned long long bits = __ballot(m != 0);
    if (lane == 0) mb[word] = bits;
  }
}

// ---------------- prep: V [bh][L][64] -> Vt [bh][64][L] ----------------
__global__ __launch_bounds__(256) void k_vtrans(const u16* __restrict__ V, u16* __restrict__ Vt) {
  __shared__ u16 tile[64][72];
  const int bh = blockIdx.x >> 5;
  const int l0 = (blockIdx.x & 31) * 64;
  const int t = threadIdx.x;
  const u16* src = V + ((size_t)bh*SEQ + l0)*DK;
  #pragma unroll
  for (int j=0;j<2;j++) {
    int idx = t + j*256;                 // 0..511
    int r = idx >> 3, c8 = (idx & 7)*8;
    *(u16x8*)&tile[r][c8] = *(const u16x8*)(src + (size_t)r*DK + c8);
  }
  __syncthreads();
  u16* dst = Vt + (size_t)bh*DK*SEQ + l0;
  #pragma unroll
  for (int j=0;j<2;j++) {
    int idx = t + j*256;
    int d = idx >> 3, k8 = (idx & 7)*8;
    u16x8 o;
    #pragma unroll
    for (int e=0;e<8;e++) o[e] = tile[k8 + e][d];
    *(u16x8*)(dst + (size_t)d*SEQ + k8) = o;
  }
}

// ---------------- 128x128 MFMA GEMM, C = A @ Bt^T (+epilogue) ----------------
template<int EPI>
__global__ __launch_bounds__(256) void k_gemm(const u16* __restrict__ A, const u16* __restrict__ Bt,
                                              const int M, const int N, const int K, const int nbm,
                                              const float* __restrict__ bq, const float* __restrict__ bk,
                                              const float* __restrict__ bv,
                                              u16* __restrict__ Qo, u16* __restrict__ Ko, u16* __restrict__ Vo,
                                              const float* __restrict__ bo, float* __restrict__ out) {
  __shared__ u16 As[128*32];
  __shared__ u16 Bs[128*32];
  const int t = threadIdx.x, lane = t & 63, w = t >> 6;
  const int bm = blockIdx.x % nbm, bn = blockIdx.x / nbm;
  const int brow = bm*128, bcol = bn*128;

  const int srow = w*32 + (lane >> 2);
  const int sswz = (lane & 3) ^ ((lane >> 2) & 3);
  const u16* aS0 = A  + (size_t)(brow + srow)*K + sswz*8;
  const u16* aS1 = aS0 + (size_t)16*K;
  const u16* bS0 = Bt + (size_t)(bcol + srow)*K + sswz*8;
  const u16* bS1 = bS0 + (size_t)16*K;
  u16* aD0 = As + w*1024; u16* aD1 = aD0 + 512;
  u16* bD0 = Bs + w*1024; u16* bD1 = bD0 + 512;

  const int wr = w >> 1, wc = w & 1;
  const int slotA = (lane >> 4) ^ (lane & 3);
  const u16* aRd = As + (wr*64 + (lane & 15))*32 + slotA*8;
  const u16* bRd = Bs + (wc*64 + (lane & 15))*32 + slotA*8;

  f32x4 acc[4][4];
  #pragma unroll
  for (int i=0;i<4;i++)
    #pragma unroll
    for (int j=0;j<4;j++) acc[i][j] = (f32x4){0.f,0.f,0.f,0.f};

  for (int kt = 0; kt < K; kt += 32) {
    gl_lds16(aS0 + kt, aD0);
    gl_lds16(aS1 + kt, aD1);
    gl_lds16(bS0 + kt, bD0);
    gl_lds16(bS1 + kt, bD1);
    __syncthreads();
    bf16x8 af[4], bfr[4];
    #pragma unroll
    for (int m=0;m<4;m++) af[m] = ld_frag(aRd + m*512);
    #pragma unroll
    for (int n=0;n<4;n++) bfr[n] = ld_frag(bRd + n*512);
    #pragma unroll
    for (int m=0;m<4;m++)
      #pragma unroll
      for (int n=0;n<4;n++)
        acc[m][n] = __builtin_amdgcn_mfma_f32_16x16x32_bf16(af[m], bfr[n], acc[m][n], 0,0,0);
    __syncthreads();
  }

  const int orow = brow + wr*64 + (lane >> 4)*4;
  const int ocol = bcol + wc*64 + (lane & 15);
  if (EPI == 0) {
    const int mat = ocol >> 10;
    const float* bias = (mat==0) ? bq : (mat==1) ? bk : bv;
    u16* outp = (mat==0) ? Qo : (mat==1) ? Ko : Vo;
    // fold 1/sqrt(dk) AND log2(e) into Q so attention softmax runs in exp2 domain
    const float scal = (mat==0) ? 0.125f*1.4426950408889634f : 1.0f;
    #pragma unroll
    for (int m=0;m<4;m++) {
      #pragma unroll
      for (int n=0;n<4;n++) {
        int col = ocol + n*16;
        int c = col & 1023;
        float bb = bias[c];
        int h = c >> 6, d = c & 63;
        #pragma unroll
        for (int j=0;j<4;j++) {
          int row = orow + m*16 + j;
          int b = row >> 11, l = row & 2047;
          float v = (acc[m][n][j] + bb) * scal;
          outp[(((size_t)(b*NHEAD + h)*SEQ + l) << 6) + d] = f2bf(v);
        }
      }
    }
  } else {
    #pragma unroll
    for (int m=0;m<4;m++)
      #pragma unroll
      for (int n=0;n<4;n++) {
        int col = ocol + n*16;
        float bb = bo[col];
        #pragma unroll
        for (int j=0;j<4;j++) {
          int row = orow + m*16 + j;
          out[(size_t)row*N + col] = acc[m][n][j] + bb;
        }
      }
  }
}

// ---------------- flash attention, 32x32 swapped-operand structure ----------------
// Block: 4 waves x 32 q-rows = 128 q/block. KV tile = 64 keys staged in LDS.
// S^T = mfma(K, Q): lane owns q = lane&31 -> softmax stats lane-local (1 shfl_xor(32)).
// O^T = mfma(V^T, P^T): accumulator cols = q -> rescale/normalize lane-local.
// P f32 -> bf16 PA fragments via v_cvt_pk_bf16_f32 + v_permlane32_swap_b32 (T12).
__global__ __launch_bounds__(256) void k_attn(const u16* __restrict__ Q, const u16* __restrict__ K,
                                              const u16* __restrict__ Vt,
                                              const unsigned long long* __restrict__ MB,
                                              u16* __restrict__ AO) {
  __shared__ u16 Ks[64*64];   // [key][dk], slot-swizzled: phys = slot ^ (key&7)
  __shared__ u16 Vs[64*64];   // [d][key],  slot-swizzled: phys = slot ^ (d&7)
  const int t = threadIdx.x, lane = t & 63, w = t >> 6;
  const int bh = blockIdx.x >> 4;
  const int q0 = (blockIdx.x & 15) * 128;
  const int b = bh >> 4, h = bh & 15;
  const int lq = lane & 31, hi = lane >> 5, l7 = lane & 7;

  const int qg = q0 + w*32 + lq;
  // Q B-fragments: lane needs Q[qg][ks*16 + hi*8 + 0..7]
  const u16* qp = Q + ((size_t)bh*SEQ + qg)*DK + hi*8;
  bf16x8 qf[4];
  #pragma unroll
  for (int ks=0;ks<4;ks++) qf[ks] = ld_frag(qp + ks*16);

  // staging: K tile 8KB, V tile 8KB; wave w stages rows w*16..w*16+15 of each.
  const int srow = w*16 + (lane >> 3);
  const int sswz = l7 ^ ((lane >> 3) & 7);        // pre-swizzled global source
  const u16* kS0 = K  + ((size_t)bh*SEQ + srow)*DK + sswz*8;
  const u16* kS1 = kS0 + 8*DK;
  const u16* vS0 = Vt + ((size_t)bh*DK + srow)*SEQ + sswz*8;
  const u16* vS1 = vS0 + 8*SEQ;
  u16* kD0 = Ks + w*1024; u16* kD1 = kD0 + 512;
  u16* vD0 = Vs + w*1024; u16* vD1 = vD0 + 512;

  f32x16 o0 = 0.f, o1 = 0.f;
  float m_run = -1e30f, l_run = 0.f;
  const unsigned long long* mbp = MB + ((size_t)b*SEQ + qg)*32;

  for (int kt = 0; kt < SEQ/64; ++kt) {
    gl_lds16(kS0, kD0); gl_lds16(kS1, kD1);
    gl_lds16(vS0, vD0); gl_lds16(vS1, vD1);
    kS0 += 64*DK; kS1 += 64*DK; vS0 += 64; vS1 += 64;
    __syncthreads();

    // ---- S^T: 2 key-tiles of 32 ----
    f32x16 s0 = 0.f, s1 = 0.f;
    #pragma unroll
    for (int ks=0;ks<4;ks++) {
      // K A-frag: row = lq (+32 for tile1), logical slot ks*2+hi, phys ^= (row&7)=l7
      const int ph = (ks*2 + hi) ^ l7;
      bf16x8 kf0 = ld_frag(Ks + lq*64 + ph*8);
      bf16x8 kf1 = ld_frag(Ks + (32+lq)*64 + ph*8);
      s0 = __builtin_amdgcn_mfma_f32_32x32x16_bf16(kf0, qf[ks], s0, 0,0,0);
      s1 = __builtin_amdgcn_mfma_f32_32x32x16_bf16(kf1, qf[ks], s1, 0,0,0);
    }

    unsigned long long mb = mbp[kt];
    if (!__all(mb == ~0ull)) {
      #pragma unroll
      for (int r=0;r<16;r++) {
        int kl = (r&3) + 8*(r>>2) + 4*hi;
        if (!((mb >> kl) & 1ull)) s0[r] = -1e9f;
        if (!((mb >> (kl+32)) & 1ull)) s1[r] = -1e9f;
      }
    }

    // ---- online softmax (q = lq; stats lane-local, 1 cross-half shfl) ----
    float mx = -1e30f;
    #pragma unroll
    for (int r=0;r<16;r++) { mx = fmaxf(mx, s0[r]); mx = fmaxf(mx, s1[r]); }
    mx = fmaxf(mx, __shfl_xor(mx, 32));
    float m_new = fmaxf(m_run, mx);
    float corr = __builtin_amdgcn_exp2f(m_run - m_new);
    float ps = 0.f;
    #pragma unroll
    for (int r=0;r<16;r++) {
      s0[r] = __builtin_amdgcn_exp2f(s0[r] - m_new); ps += s0[r];
      s1[r] = __builtin_amdgcn_exp2f(s1[r] - m_new); ps += s1[r];
    }
    ps += __shfl_xor(ps, 32);
    l_run = l_run * corr + ps;
    m_run = m_new;
    #pragma unroll
    for (int r=0;r<16;r++) { o0[r] *= corr; o1[r] *= corr; }

    // ---- P -> bf16 PA fragments (cvt_pk + permlane32_swap), then PV ----
    #pragma unroll
    for (int kt2=0;kt2<2;kt2++) {
      const f32x16& sv = kt2 ? s1 : s0;
      u32 w0 = cvtpk(sv[0],  sv[1]),  w1 = cvtpk(sv[2],  sv[3]);
      u32 w2 = cvtpk(sv[4],  sv[5]),  w3 = cvtpk(sv[6],  sv[7]);
      u32 w4 = cvtpk(sv[8],  sv[9]),  w5 = cvtpk(sv[10], sv[11]);
      u32 w6 = cvtpk(sv[12], sv[13]), w7 = cvtpk(sv[14], sv[15]);
      asm volatile("v_permlane32_swap_b32 %0, %1" : "+v"(w0), "+v"(w2));
      asm volatile("v_permlane32_swap_b32 %0, %1" : "+v"(w1), "+v"(w3));
      asm volatile("v_permlane32_swap_b32 %0, %1" : "+v"(w4), "+v"(w6));
      asm volatile("v_permlane32_swap_b32 %0, %1" : "+v"(w5), "+v"(w7));
      bf16x8 pa0 = __builtin_bit_cast(bf16x8, (u32x4){w0, w1, w2, w3});
      bf16x8 pa1 = __builtin_bit_cast(bf16x8, (u32x4){w4, w5, w6, w7});
      // V^T A-frags: row d = dt*32+lq, key-slice ks = kt2*2 + {0,1}
      const int ph0 = ((kt2*2+0)*2 + hi) ^ l7;
      const int ph1 = ((kt2*2+1)*2 + hi) ^ l7;
      bf16x8 v00 = ld_frag(Vs + lq*64      + ph0*8);
      bf16x8 v01 = ld_frag(Vs + lq*64      + ph1*8);
      bf16x8 v10 = ld_frag(Vs + (32+lq)*64 + ph0*8);
      bf16x8 v11 = ld_frag(Vs + (32+lq)*64 + ph1*8);
      o0 = __builtin_amdgcn_mfma_f32_32x32x16_bf16(v00, pa0, o0, 0,0,0);
      o0 = __builtin_amdgcn_mfma_f32_32x32x16_bf16(v01, pa1, o0, 0,0,0);
      o1 = __builtin_amdgcn_mfma_f32_32x32x16_bf16(v10, pa0, o1, 0,0,0);
      o1 = __builtin_amdgcn_mfma_f32_32x32x16_bf16(v11, pa1, o1, 0,0,0);
    }
    __syncthreads();
  }

  // ---- epilogue: O^T lane-local normalize; lane q=lq holds d rows crow(r,hi) ----
  const float inv = 1.0f / l_run;
  size_t base = ((size_t)(b*SEQ + qg))*D_MODEL + h*DK;
  #pragma unroll
  for (int rr=0;rr<4;rr++) {
    u16x4 g0, g1;
    #pragma unroll
    for (int i=0;i<4;i++) { g0[i] = f2bf(o0[rr*4+i]*inv); g1[i] = f2bf(o1[rr*4+i]*inv); }
    *(u16x4*)(AO + base + rr*8 + hi*4)      = g0;
    *(u16x4*)(AO + base + 32 + rr*8 + hi*4) = g1;
  }
}

extern "C" void kernel_launch(void* const* d_in, const int* in_sizes, int n_in,
                              void* d_out, int out_size, void* d_ws, size_t ws_size,
                              hipStream_t stream) {
  const float* x  = (const float*)d_in[0];
  const int*  msk = (const int*)d_in[1];
  const float* wq = (const float*)d_in[2];
  const float* bq = (const float*)d_in[3];
  const float* wk = (const float*)d_in[4];
  const float* bk = (const float*)d_in[5];
  const float* wv = (const float*)d_in[6];
  const float* bv = (const float*)d_in[7];
  const float* wo = (const float*)d_in[8];
  const float* bo = (const float*)d_in[9];
  float* out = (float*)d_out;

  char* ws = (char*)d_ws;
  size_t off = 0;
  u16* Xb   = (u16*)(ws + off); off += (size_t)MTOT*D_MODEL*2;
  u16* Wqkv = (u16*)(ws + off); off += (size_t)3*D_MODEL*D_MODEL*2;
  u16* Wot  = (u16*)(ws + off); off += (size_t)D_MODEL*D_MODEL*2;
  u16* Qb   = (u16*)(ws + off); off += (size_t)BATCH*NHEAD*SEQ*DK*2;
  u16* Kb   = (u16*)(ws + off); off += (size_t)BATCH*NHEAD*SEQ*DK*2;
  u16* Vb   = (u16*)(ws + off); off += (size_t)BATCH*NHEAD*SEQ*DK*2;
  u16* Vtb  = (u16*)(ws + off); off += (size_t)BATCH*NHEAD*SEQ*DK*2;
  u16* AO   = (u16*)(ws + off); off += (size_t)MTOT*D_MODEL*2;
  unsigned long long* Mb = (unsigned long long*)(ws + off);

  k_cvt_x<<<MTOT*D_MODEL/4/256, 256, 0, stream>>>(x, Xb);
  k_wtrans<<<dim3(32,32,4), 256, 0, stream>>>(wq, wk, wv, wo, Wqkv, Wot);
  k_maskpack<<<1024, 256, 0, stream>>>(msk, Mb);
  k_gemm<0><<<(MTOT/128)*(3*D_MODEL/128), 256, 0, stream>>>(
      Xb, Wqkv, MTOT, 3*D_MODEL, D_MODEL, MTOT/128,
      bq, bk, bv, Qb, Kb, Vb, nullptr, nullptr);
  k_vtrans<<<BATCH*NHEAD*(SEQ/64), 256, 0, stream>>>(Vb, Vtb);
  k_attn<<<BATCH*NHEAD*(SEQ/128), 256, 0, stream>>>(Qb, Kb, Vtb, Mb, AO);
  k_gemm<1><<<(MTOT/128)*(D_MODEL/128), 256, 0, stream>>>(
      AO, Wot, MTOT, D_MODEL, D_MODEL, MTOT/128,
      nullptr, nullptr, nullptr, nullptr, nullptr, nullptr, bo, out);
}